// Round 1
// baseline (2138.543 us; speedup 1.0000x reference)
//
#include <hip/hip_runtime.h>
#include <math.h>

#define BB 8192
#define TT 60
#define NU 100
#define NI 7

// wave = 1 trial; lane l owns units l and 64+l (second valid only for l<36).
// W_rec rows live in VGPRs (200 regs/lane). y broadcast via __shfl (readlane).
// No LDS, no __syncthreads — fully wave-synchronous.
__global__ __launch_bounds__(256, 2)
void drr_kernel(const float* __restrict__ y0,
                const float* __restrict__ noise,
                const int*   __restrict__ stim_idx,
                const int*   __restrict__ rew_idx,
                const int*   __restrict__ instr_in,
                const float* __restrict__ W_in_raw,
                const float* __restrict__ W_rec,
                const float* __restrict__ b_rec,
                const float* __restrict__ w_out,
                const float* __restrict__ b_out,
                float* __restrict__ out)
{
    const int lane  = threadIdx.x & 63;
    const int wid   = threadIdx.x >> 6;
    const int trial = blockIdx.x * 4 + wid;

    const int  u1   = lane;
    const int  u2   = 64 + lane;
    const bool has2 = (u2 < NU);
    const int  u2c  = has2 ? u2 : (NU - 1);   // clamped for safe loads

    // per-trial scalars (wave-uniform)
    const int  stim    = stim_idx[trial];
    const int  rew     = rew_idx[trial];
    const bool is_rew  = (stim == rew);
    const bool instr_b = (instr_in[trial] > 0);

    // recurrent weight rows -> registers
    float w1[NU], w2[NU];
    #pragma unroll
    for (int k = 0; k < NU; ++k) {
        w1[k] = W_rec[u1  * NU + k];
        w2[k] = W_rec[u2c * NU + k];
    }

    // W_in columns (abs applied)
    const float wi6_1 = fabsf(W_in_raw[u1  * NI + 6]);
    const float wis_1 = fabsf(W_in_raw[u1  * NI + stim]);
    const float wr_1  = fabsf(W_in_raw[u1  * NI + 4]);
    const float wl_1  = fabsf(W_in_raw[u1  * NI + 5]);
    const float wi6_2 = fabsf(W_in_raw[u2c * NI + 6]);
    const float wis_2 = fabsf(W_in_raw[u2c * NI + stim]);
    const float wr_2  = fabsf(W_in_raw[u2c * NI + 4]);
    const float wl_2  = fabsf(W_in_raw[u2c * NI + 5]);

    const float br_1 = b_rec[u1];
    const float br_2 = b_rec[u2c];
    const float wo_1 = w_out[u1];
    const float wo_2 = has2 ? w_out[u2] : 0.0f;   // zero => unit2 never pollutes z
    const float bo   = b_out[0];

    float y1 = y0[trial * NU + u1];
    float y2 = has2 ? y0[trial * NU + u2] : 0.0f;

    const float NS = 0.09486832980505138f; // 0.15 * sqrt(2*0.2), fp64-rounded

    // control state, replicated wave-uniform in every lane
    bool licked = false, instr_fired = false;
    int  lick_t = TT + 1;

    const int nbase = trial * (TT * NU);
    // noise prefetch (t=0)
    float e1n = noise[nbase + u1];
    float e2n = noise[nbase + u2c];

    // output section pointers (flat tuple order)
    float* uout  = out;                        // B*T*7
    float* tout  = out  + BB * TT * NI;        // B*T
    float* rout  = tout + BB * TT;             // B*T
    float* lout  = rout + BB * TT;             // B
    float* dout  = lout + BB;                  // B
    float* zout  = dout + BB;                  // B*T
    float* yfout = zout + BB * TT;             // B*100

    for (int t = 0; t < TT; ++t) {
        const float e1 = e1n, e2 = e2n;
        if (t < TT - 1) {
            e1n = noise[nbase + (t + 1) * NU + u1];
            e2n = noise[nbase + (t + 1) * NU + u2c];
        }

        const float sm = (t >= 10 && t < 15) ? 1.0f : 0.0f;  // stim_mask
        const float rm = (t >= 20 && t < 35) ? 1.0f : 0.0f;  // resp_mask

        // reward routing logic (state from previous step)
        const bool delivered    = instr_fired || (licked && is_rew);
        const bool fire         = instr_b && !delivered && (t == 30);
        instr_fired             = instr_fired || fire;
        const bool instr_active = instr_fired && (t >= 30) && (t < 35);
        const bool lick_dyn     = licked && (t > lick_t) && (t < lick_t + 5);
        const float a_rew  = (instr_active ? 1.0f : 0.0f) + ((lick_dyn && is_rew) ? 1.0f : 0.0f);
        const float a_lick = lick_dyn ? 1.0f : 0.0f;

        // pre = wu_t + add + noise, then += W_rec @ y
        float pre1 = br_1 + rm * wi6_1 + sm * wis_1 + a_rew * wr_1 + a_lick * wl_1 + NS * e1;
        float pre2 = br_2 + rm * wi6_2 + sm * wis_2 + a_rew * wr_2 + a_lick * wl_2 + NS * e2;
        float p1b = 0.0f, p2b = 0.0f;  // secondary accumulators for ILP (4 chains)

        #pragma unroll
        for (int k = 0; k < 32; ++k) {
            const float yk = __shfl(y1, k);
            pre1 += yk * w1[k];
            pre2 += yk * w2[k];
        }
        #pragma unroll
        for (int k = 32; k < 64; ++k) {
            const float yk = __shfl(y1, k);
            p1b += yk * w1[k];
            p2b += yk * w2[k];
        }
        #pragma unroll
        for (int k = 64; k < NU; ++k) {
            const float yk = __shfl(y2, k - 64);
            pre1 += yk * w1[k];
            pre2 += yk * w2[k];
        }
        pre1 += p1b;
        pre2 += p2b;

        y1 = 0.8f * y1 + 0.2f * fmaxf(pre1, 0.0f);
        y2 = 0.8f * y2 + 0.2f * fmaxf(pre2, 0.0f);

        // z = sigmoid(y . w_out + b_out) — butterfly sum over 64 lanes
        float part = y1 * wo_1 + y2 * wo_2;
        #pragma unroll
        for (int off = 32; off >= 1; off >>= 1)
            part += __shfl_xor(part, off);
        const float x = part + bo;
        const float z = 1.0f / (1.0f + expf(-x));

        const bool in_resp = (t >= 20) && (t < 35);
        const bool trig    = in_resp && !licked && (z > 0.5f);
        if (trig) lick_t = t;          // wave-uniform
        licked = licked || trig;
        const bool u5 = licked && (t >= lick_t) && (t < lick_t + 5);
        const bool u4 = instr_active || (u5 && is_rew);

        // per-step outputs
        const int bt = trial * TT + t;
        if (lane < NI) {
            float uv = 0.0f;
            if (lane == stim) uv = sm;                 // stim in [0,4)
            if (lane == 4)    uv = u4 ? 1.0f : 0.0f;
            if (lane == 5)    uv = u5 ? 1.0f : 0.0f;
            if (lane == 6)    uv = rm;
            uout[bt * NI + lane] = uv;
        } else if (lane == 8) {
            tout[bt] = is_rew ? rm : 0.0f;
        } else if (lane == 9) {
            rout[bt] = rm;
        } else if (lane == 10) {
            zout[bt] = z;
        }
    }

    if (lane == 0) {
        lout[trial] = licked ? 1.0f : 0.0f;
        dout[trial] = (instr_fired || (licked && is_rew)) ? 1.0f : 0.0f;
    }
    yfout[trial * NU + u1] = y1;
    if (has2) yfout[trial * NU + u2] = y2;
}

extern "C" void kernel_launch(void* const* d_in, const int* in_sizes, int n_in,
                              void* d_out, int out_size, void* d_ws, size_t ws_size,
                              hipStream_t stream) {
    const float* y0       = (const float*)d_in[0];
    const float* noise    = (const float*)d_in[1];
    const int*   stim     = (const int*)  d_in[2];
    const int*   rew      = (const int*)  d_in[3];
    const int*   instr    = (const int*)  d_in[4];
    const float* W_in_raw = (const float*)d_in[5];
    const float* W_rec    = (const float*)d_in[6];
    const float* b_rec    = (const float*)d_in[7];
    const float* w_out    = (const float*)d_in[8];
    const float* b_out    = (const float*)d_in[9];
    float* out = (float*)d_out;

    // 4 trials per 256-thread block (1 wave per trial)
    drr_kernel<<<BB / 4, 256, 0, stream>>>(y0, noise, stim, rew, instr,
                                           W_in_raw, W_rec, b_rec, w_out, b_out, out);
}

// Round 2
// 620.688 us; speedup vs baseline: 3.4454x; 3.4454x over previous
//
#include <hip/hip_runtime.h>
#include <math.h>

#define BB 8192
#define TT 60
#define NU 100
#define NI 7

// ---- repetition macros (guarantee full unroll + literal lane indices) ----
#define L32A(M) M(0) M(1) M(2) M(3) M(4) M(5) M(6) M(7) M(8) M(9) M(10) M(11) \
  M(12) M(13) M(14) M(15) M(16) M(17) M(18) M(19) M(20) M(21) M(22) M(23) \
  M(24) M(25) M(26) M(27) M(28) M(29) M(30) M(31)
#define L32B(M) M(32) M(33) M(34) M(35) M(36) M(37) M(38) M(39) M(40) M(41) \
  M(42) M(43) M(44) M(45) M(46) M(47) M(48) M(49) M(50) M(51) M(52) M(53) \
  M(54) M(55) M(56) M(57) M(58) M(59) M(60) M(61) M(62) M(63)
#define P36(M) M(64,0) M(65,1) M(66,2) M(67,3) M(68,4) M(69,5) M(70,6) \
  M(71,7) M(72,8) M(73,9) M(74,10) M(75,11) M(76,12) M(77,13) M(78,14) \
  M(79,15) M(80,16) M(81,17) M(82,18) M(83,19) M(84,20) M(85,21) M(86,22) \
  M(87,23) M(88,24) M(89,25) M(90,26) M(91,27) M(92,28) M(93,29) M(94,30) \
  M(95,31) M(96,32) M(97,33) M(98,34) M(99,35)

// weight declarations: w1_k = W_rec[u1][k], w2_k = W_rec[u2c][k]
#define DW(k)    const float w1_##k = W_rec[u1o + k]; const float w2_##k = W_rec[u2o + k];
#define DW2(k,j) DW(k)

// MAC steps: broadcast y_k via v_readlane (SGPR), fmac into per-lane accs
#define RL(v,l) __int_as_float(__builtin_amdgcn_readlane(__float_as_int(v), l))
#define MACA(k)   { const float yk = RL(y1, k);  pre1 += yk * w1_##k; pre2 += yk * w2_##k; }
#define MACB(k)   { const float yk = RL(y1, k);  p1b  += yk * w1_##k; p2b  += yk * w2_##k; }
#define MACC(k,j) { const float yk = RL(y2, j);  pre1 += yk * w1_##k; pre2 += yk * w2_##k; }

// wave = 1 trial; lane l owns units l and 64+l (second valid only for l<36).
// W_rec rows live in 200 macro-declared scalar registers. No LDS, no barriers.
__global__ __launch_bounds__(256, 2)
void drr_kernel(const float* __restrict__ y0,
                const float* __restrict__ noise,
                const int*   __restrict__ stim_idx,
                const int*   __restrict__ rew_idx,
                const int*   __restrict__ instr_in,
                const float* __restrict__ W_in_raw,
                const float* __restrict__ W_rec,
                const float* __restrict__ b_rec,
                const float* __restrict__ w_out,
                const float* __restrict__ b_out,
                float* __restrict__ out)
{
    const int lane  = threadIdx.x & 63;
    const int wid   = threadIdx.x >> 6;
    const int trial = blockIdx.x * 4 + wid;

    const int  u1   = lane;
    const int  u2   = 64 + lane;
    const bool has2 = (u2 < NU);
    const int  u2c  = has2 ? u2 : (NU - 1);   // clamped for safe loads

    const int u1o = u1  * NU;
    const int u2o = u2c * NU;

    // per-trial scalars (wave-uniform)
    const int  stim    = stim_idx[trial];
    const int  rew     = rew_idx[trial];
    const bool is_rew  = (stim == rew);
    const bool instr_b = (instr_in[trial] > 0);

    // recurrent weight rows -> 200 scalar registers (no alloca)
    L32A(DW) L32B(DW) P36(DW2)

    // W_in columns (abs applied)
    const float wi6_1 = fabsf(W_in_raw[u1  * NI + 6]);
    const float wis_1 = fabsf(W_in_raw[u1  * NI + stim]);
    const float wr_1  = fabsf(W_in_raw[u1  * NI + 4]);
    const float wl_1  = fabsf(W_in_raw[u1  * NI + 5]);
    const float wi6_2 = fabsf(W_in_raw[u2c * NI + 6]);
    const float wis_2 = fabsf(W_in_raw[u2c * NI + stim]);
    const float wr_2  = fabsf(W_in_raw[u2c * NI + 4]);
    const float wl_2  = fabsf(W_in_raw[u2c * NI + 5]);

    const float br_1 = b_rec[u1];
    const float br_2 = b_rec[u2c];
    const float wo_1 = w_out[u1];
    const float wo_2 = has2 ? w_out[u2] : 0.0f;   // zero => unit2 never pollutes z
    const float bo   = b_out[0];

    float y1 = y0[trial * NU + u1];
    float y2 = has2 ? y0[trial * NU + u2] : 0.0f;

    const float NS = 0.09486832980505138f; // 0.15 * sqrt(2*0.2)

    // control state, replicated wave-uniform in every lane
    bool licked = false, instr_fired = false;
    int  lick_t = TT + 1;

    const int nbase = trial * (TT * NU);
    float e1n = noise[nbase + u1];
    float e2n = noise[nbase + u2c];

    // output section pointers (flat tuple order)
    float* uout  = out;                        // B*T*7
    float* tout  = out  + BB * TT * NI;        // B*T
    float* rout  = tout + BB * TT;             // B*T
    float* lout  = rout + BB * TT;             // B
    float* dout  = lout + BB;                  // B
    float* zout  = dout + BB;                  // B*T
    float* yfout = zout + BB * TT;             // B*100

    for (int t = 0; t < TT; ++t) {
        const float e1 = e1n, e2 = e2n;
        if (t < TT - 1) {
            e1n = noise[nbase + (t + 1) * NU + u1];
            e2n = noise[nbase + (t + 1) * NU + u2c];
        }

        const float sm = (t >= 10 && t < 15) ? 1.0f : 0.0f;  // stim_mask
        const float rm = (t >= 20 && t < 35) ? 1.0f : 0.0f;  // resp_mask

        // reward routing logic (state from previous step)
        const bool delivered    = instr_fired || (licked && is_rew);
        const bool fire         = instr_b && !delivered && (t == 30);
        instr_fired             = instr_fired || fire;
        const bool instr_active = instr_fired && (t >= 30) && (t < 35);
        const bool lick_dyn     = licked && (t > lick_t) && (t < lick_t + 5);
        const float a_rew  = (instr_active ? 1.0f : 0.0f) + ((lick_dyn && is_rew) ? 1.0f : 0.0f);
        const float a_lick = lick_dyn ? 1.0f : 0.0f;

        float pre1 = br_1 + rm * wi6_1 + sm * wis_1 + a_rew * wr_1 + a_lick * wl_1 + NS * e1;
        float pre2 = br_2 + rm * wi6_2 + sm * wis_2 + a_rew * wr_2 + a_lick * wl_2 + NS * e2;
        float p1b = 0.0f, p2b = 0.0f;

        L32A(MACA)      // k = 0..31   -> pre1/pre2
        L32B(MACB)      // k = 32..63  -> p1b/p2b
        P36(MACC)       // k = 64..99  -> pre1/pre2 (y2 lanes 0..35)

        pre1 += p1b;
        pre2 += p2b;

        y1 = 0.8f * y1 + 0.2f * fmaxf(pre1, 0.0f);
        y2 = 0.8f * y2 + 0.2f * fmaxf(pre2, 0.0f);

        // z = sigmoid(y . w_out + b_out) — butterfly sum over 64 lanes
        float part = y1 * wo_1 + y2 * wo_2;
        #pragma unroll
        for (int off = 32; off >= 1; off >>= 1)
            part += __shfl_xor(part, off);
        const float x = part + bo;
        const float z = 1.0f / (1.0f + expf(-x));

        const bool in_resp = (t >= 20) && (t < 35);
        const bool trig    = in_resp && !licked && (z > 0.5f);
        if (trig) lick_t = t;          // wave-uniform
        licked = licked || trig;
        const bool u5 = licked && (t >= lick_t) && (t < lick_t + 5);
        const bool u4 = instr_active || (u5 && is_rew);

        // per-step outputs
        const int bt = trial * TT + t;
        if (lane < NI) {
            float uv = 0.0f;
            if (lane == stim) uv = sm;                 // stim in [0,4)
            if (lane == 4)    uv = u4 ? 1.0f : 0.0f;
            if (lane == 5)    uv = u5 ? 1.0f : 0.0f;
            if (lane == 6)    uv = rm;
            uout[bt * NI + lane] = uv;
        } else if (lane == 8) {
            tout[bt] = is_rew ? rm : 0.0f;
        } else if (lane == 9) {
            rout[bt] = rm;
        } else if (lane == 10) {
            zout[bt] = z;
        }
    }

    if (lane == 0) {
        lout[trial] = licked ? 1.0f : 0.0f;
        dout[trial] = (instr_fired || (licked && is_rew)) ? 1.0f : 0.0f;
    }
    yfout[trial * NU + u1] = y1;
    if (has2) yfout[trial * NU + u2] = y2;
}

extern "C" void kernel_launch(void* const* d_in, const int* in_sizes, int n_in,
                              void* d_out, int out_size, void* d_ws, size_t ws_size,
                              hipStream_t stream) {
    const float* y0       = (const float*)d_in[0];
    const float* noise    = (const float*)d_in[1];
    const int*   stim     = (const int*)  d_in[2];
    const int*   rew      = (const int*)  d_in[3];
    const int*   instr    = (const int*)  d_in[4];
    const float* W_in_raw = (const float*)d_in[5];
    const float* W_rec    = (const float*)d_in[6];
    const float* b_rec    = (const float*)d_in[7];
    const float* w_out    = (const float*)d_in[8];
    const float* b_out    = (const float*)d_in[9];
    float* out = (float*)d_out;

    drr_kernel<<<BB / 4, 256, 0, stream>>>(y0, noise, stim, rew, instr,
                                           W_in_raw, W_rec, b_rec, w_out, b_out, out);
}

// Round 3
// 619.333 us; speedup vs baseline: 3.4530x; 1.0022x over previous
//
#include <hip/hip_runtime.h>
#include <math.h>

#define BB 8192
#define TT 60
#define NU 100
#define NI 7

typedef float v2f __attribute__((ext_vector_type(2)));

// lane l (<50) owns unit pair (2l, 2l+1); weights held as 100 v2f registers
// -> v_pk_fma_f32 does both units' MACs in one instruction.
#define FOR50(M) M(0) M(1) M(2) M(3) M(4) M(5) M(6) M(7) M(8) M(9) \
  M(10) M(11) M(12) M(13) M(14) M(15) M(16) M(17) M(18) M(19) \
  M(20) M(21) M(22) M(23) M(24) M(25) M(26) M(27) M(28) M(29) \
  M(30) M(31) M(32) M(33) M(34) M(35) M(36) M(37) M(38) M(39) \
  M(40) M(41) M(42) M(43) M(44) M(45) M(46) M(47) M(48) M(49)

// weight decls: wA_sl = column 2*sl for both owned units; wB_sl = column 2*sl+1
#define DECLW(sl) \
  const v2f wA_##sl = { W_rec[uao + 2*(sl)],     W_rec[ubo + 2*(sl)]     }; \
  const v2f wB_##sl = { W_rec[uao + 2*(sl) + 1], W_rec[ubo + 2*(sl) + 1] };

#define RL(v,l) __int_as_float(__builtin_amdgcn_readlane(__float_as_int(v), l))

// MAC: broadcast y_{2sl} (lane sl, comp x) and y_{2sl+1} (lane sl, comp y),
// packed-FMA into one of 4 accumulator chains (literal sl folds the branch).
#define MAC(sl) { \
  const float ya = RL(yy.x, sl); \
  const float yb = RL(yy.y, sl); \
  if ((sl) & 1) { accB0 += ya * wA_##sl; accB1 += yb * wB_##sl; } \
  else          { accA0 += ya * wA_##sl; accA1 += yb * wB_##sl; } }

__global__ __launch_bounds__(256, 2)
void drr_kernel(const float* __restrict__ y0,
                const float* __restrict__ noise,
                const int*   __restrict__ stim_idx,
                const int*   __restrict__ rew_idx,
                const int*   __restrict__ instr_in,
                const float* __restrict__ W_in_raw,
                const float* __restrict__ W_rec,
                const float* __restrict__ b_rec,
                const float* __restrict__ w_out,
                const float* __restrict__ b_out,
                float* __restrict__ out)
{
    const int lane  = threadIdx.x & 63;
    const int wid   = threadIdx.x >> 6;
    const int trial = blockIdx.x * 4 + wid;

    const bool act = (lane < 50);              // active unit-pair lanes
    const int  la  = act ? lane : 49;          // clamped
    const int  ua  = 2 * la;                   // first unit
    const int  uao = ua * NU;
    const int  ubo = uao + NU;                 // second unit's row

    // per-trial scalars (wave-uniform)
    const int  stim    = stim_idx[trial];
    const int  rew     = rew_idx[trial];
    const bool is_rew  = (stim == rew);
    const bool instr_b = (instr_in[trial] > 0);

    // 100 v2f weight registers (200 VGPRs), even-aligned pairs
    FOR50(DECLW)

    // W_in columns (abs applied), packed per unit pair
    const v2f wi6 = { fabsf(W_in_raw[ua * NI + 6]),    fabsf(W_in_raw[(ua+1) * NI + 6]) };
    const v2f wis = { fabsf(W_in_raw[ua * NI + stim]), fabsf(W_in_raw[(ua+1) * NI + stim]) };
    const v2f wr  = { fabsf(W_in_raw[ua * NI + 4]),    fabsf(W_in_raw[(ua+1) * NI + 4]) };
    const v2f wl  = { fabsf(W_in_raw[ua * NI + 5]),    fabsf(W_in_raw[(ua+1) * NI + 5]) };
    const v2f br  = { b_rec[ua], b_rec[ua + 1] };
    const v2f wo  = act ? (v2f){ w_out[ua], w_out[ua + 1] } : (v2f){ 0.0f, 0.0f };
    const float bo = b_out[0];

    const v2f* y0v = (const v2f*)(y0 + trial * NU);
    v2f yy = y0v[la];

    const float NS = 0.09486832980505138f; // 0.15 * sqrt(2*0.2)

    bool licked = false, instr_fired = false;
    int  lick_t = TT + 1;

    const float* nbase = noise + trial * (TT * NU);
    v2f en = ((const v2f*)nbase)[la];          // t=0 prefetch (8B load)

    // output section pointers (flat tuple order)
    float* uout  = out;                        // B*T*7
    float* tout  = out  + BB * TT * NI;        // B*T
    float* rout  = tout + BB * TT;             // B*T
    float* lout  = rout + BB * TT;             // B
    float* dout  = lout + BB;                  // B
    float* zout  = dout + BB;                  // B*T
    float* yfout = zout + BB * TT;             // B*100

    for (int t = 0; t < TT; ++t) {
        const v2f e = en;
        if (t < TT - 1)
            en = ((const v2f*)(nbase + (t + 1) * NU))[la];

        const float sm = (t >= 10 && t < 15) ? 1.0f : 0.0f;  // stim_mask
        const float rm = (t >= 20 && t < 35) ? 1.0f : 0.0f;  // resp_mask

        // reward routing (state from previous step), wave-uniform
        const bool delivered    = instr_fired || (licked && is_rew);
        const bool fire         = instr_b && !delivered && (t == 30);
        instr_fired             = instr_fired || fire;
        const bool instr_active = instr_fired && (t >= 30) && (t < 35);
        const bool lick_dyn     = licked && (t > lick_t) && (t < lick_t + 5);
        const float a_rew  = (instr_active ? 1.0f : 0.0f) + ((lick_dyn && is_rew) ? 1.0f : 0.0f);
        const float a_lick = lick_dyn ? 1.0f : 0.0f;

        v2f accA0 = br + rm * wi6 + sm * wis + a_rew * wr + a_lick * wl + NS * e;
        v2f accA1 = { 0.0f, 0.0f };
        v2f accB0 = { 0.0f, 0.0f };
        v2f accB1 = { 0.0f, 0.0f };

        FOR50(MAC)   // 100 readlane + 100 pk_fma

        const v2f pre = (accA0 + accA1) + (accB0 + accB1);
        const v2f prer = { fmaxf(pre.x, 0.0f), fmaxf(pre.y, 0.0f) };
        yy = 0.8f * yy + 0.2f * prer;

        // z = sigmoid(y . w_out + b_out) — butterfly over 64 lanes (wo=0 for lanes>=50)
        float part = yy.x * wo.x + yy.y * wo.y;
        #pragma unroll
        for (int off = 32; off >= 1; off >>= 1)
            part += __shfl_xor(part, off);
        const float x = part + bo;
        const float z = 1.0f / (1.0f + expf(-x));

        const bool in_resp = (t >= 20) && (t < 35);
        const bool trig    = in_resp && !licked && (z > 0.5f);
        if (trig) lick_t = t;          // wave-uniform
        licked = licked || trig;
        const bool u5 = licked && (t >= lick_t) && (t < lick_t + 5);
        const bool u4 = instr_active || (u5 && is_rew);

        // per-step outputs
        const int bt = trial * TT + t;
        if (lane < NI) {
            float uv = 0.0f;
            if (lane == stim) uv = sm;                 // stim in [0,4)
            if (lane == 4)    uv = u4 ? 1.0f : 0.0f;
            if (lane == 5)    uv = u5 ? 1.0f : 0.0f;
            if (lane == 6)    uv = rm;
            uout[bt * NI + lane] = uv;
        } else if (lane == 8) {
            tout[bt] = is_rew ? rm : 0.0f;
        } else if (lane == 9) {
            rout[bt] = rm;
        } else if (lane == 10) {
            zout[bt] = z;
        }
    }

    if (lane == 0) {
        lout[trial] = licked ? 1.0f : 0.0f;
        dout[trial] = (instr_fired || (licked && is_rew)) ? 1.0f : 0.0f;
    }
    if (act)
        ((v2f*)(yfout + trial * NU))[la] = yy;   // 8B store, units 2l/2l+1
}

extern "C" void kernel_launch(void* const* d_in, const int* in_sizes, int n_in,
                              void* d_out, int out_size, void* d_ws, size_t ws_size,
                              hipStream_t stream) {
    const float* y0       = (const float*)d_in[0];
    const float* noise    = (const float*)d_in[1];
    const int*   stim     = (const int*)  d_in[2];
    const int*   rew      = (const int*)  d_in[3];
    const int*   instr    = (const int*)  d_in[4];
    const float* W_in_raw = (const float*)d_in[5];
    const float* W_rec    = (const float*)d_in[6];
    const float* b_rec    = (const float*)d_in[7];
    const float* w_out    = (const float*)d_in[8];
    const float* b_out    = (const float*)d_in[9];
    float* out = (float*)d_out;

    drr_kernel<<<BB / 4, 256, 0, stream>>>(y0, noise, stim, rew, instr,
                                           W_in_raw, W_rec, b_rec, w_out, b_out, out);
}

// Round 4
// 584.746 us; speedup vs baseline: 3.6572x; 1.0591x over previous
//
#include <hip/hip_runtime.h>
#include <math.h>

#define BB 8192
#define TT 60
#define NU 100
#define NI 7

typedef float v2f __attribute__((ext_vector_type(2)));

// lane l (<50) owns unit pair (2l, 2l+1); weights held as 100 v2f registers
// -> v_pk_fma_f32 does both units' MACs in one instruction.
// __launch_bounds__(256,1): 512-reg unified budget so all 200 weight regs
// stay ARCH VGPRs (no AGPR accvgpr_read shuttle — R3's hidden cost).
#define FOR50(M) M(0) M(1) M(2) M(3) M(4) M(5) M(6) M(7) M(8) M(9) \
  M(10) M(11) M(12) M(13) M(14) M(15) M(16) M(17) M(18) M(19) \
  M(20) M(21) M(22) M(23) M(24) M(25) M(26) M(27) M(28) M(29) \
  M(30) M(31) M(32) M(33) M(34) M(35) M(36) M(37) M(38) M(39) \
  M(40) M(41) M(42) M(43) M(44) M(45) M(46) M(47) M(48) M(49)

// weight decls: wA_sl = column 2*sl for both owned units; wB_sl = column 2*sl+1
#define DECLW(sl) \
  const v2f wA_##sl = { W_rec[uao + 2*(sl)],     W_rec[ubo + 2*(sl)]     }; \
  const v2f wB_##sl = { W_rec[uao + 2*(sl) + 1], W_rec[ubo + 2*(sl) + 1] };

#define RL(v,l) __int_as_float(__builtin_amdgcn_readlane(__float_as_int(v), l))

// MAC: broadcast y_{2sl} (lane sl, comp x) and y_{2sl+1} (lane sl, comp y),
// packed-FMA into one of 4 accumulator chains (literal sl folds the branch).
#define MAC(sl) { \
  const float ya = RL(yy.x, sl); \
  const float yb = RL(yy.y, sl); \
  if ((sl) & 1) { accB0 += ya * wA_##sl; accB1 += yb * wB_##sl; } \
  else          { accA0 += ya * wA_##sl; accA1 += yb * wB_##sl; } }

// DPP add-reduce step: part += dpp_move(part, ctrl) (pure VALU, no LDS)
#define DPPADD(ctrl, rmask) { \
  const int _t = __builtin_amdgcn_update_dpp(0, __float_as_int(part), (ctrl), (rmask), 0xf, false); \
  part += __int_as_float(_t); }

__global__ __launch_bounds__(256, 1)
void drr_kernel(const float* __restrict__ y0,
                const float* __restrict__ noise,
                const int*   __restrict__ stim_idx,
                const int*   __restrict__ rew_idx,
                const int*   __restrict__ instr_in,
                const float* __restrict__ W_in_raw,
                const float* __restrict__ W_rec,
                const float* __restrict__ b_rec,
                const float* __restrict__ w_out,
                const float* __restrict__ b_out,
                float* __restrict__ out)
{
    const int lane  = threadIdx.x & 63;
    const int wid   = threadIdx.x >> 6;
    const int trial = blockIdx.x * 4 + wid;

    const bool act = (lane < 50);              // active unit-pair lanes
    const int  la  = act ? lane : 49;          // clamped
    const int  ua  = 2 * la;                   // first unit
    const int  uao = ua * NU;
    const int  ubo = uao + NU;                 // second unit's row

    // per-trial scalars (wave-uniform)
    const int  stim    = stim_idx[trial];
    const int  rew     = rew_idx[trial];
    const bool is_rew  = (stim == rew);
    const bool instr_b = (instr_in[trial] > 0);

    // 100 v2f weight registers (200 arch VGPRs), even-aligned pairs
    FOR50(DECLW)

    // W_in columns (abs applied), packed per unit pair
    const v2f wi6 = { fabsf(W_in_raw[ua * NI + 6]),    fabsf(W_in_raw[(ua+1) * NI + 6]) };
    const v2f wis = { fabsf(W_in_raw[ua * NI + stim]), fabsf(W_in_raw[(ua+1) * NI + stim]) };
    const v2f wr  = { fabsf(W_in_raw[ua * NI + 4]),    fabsf(W_in_raw[(ua+1) * NI + 4]) };
    const v2f wl  = { fabsf(W_in_raw[ua * NI + 5]),    fabsf(W_in_raw[(ua+1) * NI + 5]) };
    const v2f br  = { b_rec[ua], b_rec[ua + 1] };
    const v2f wo  = act ? (v2f){ w_out[ua], w_out[ua + 1] } : (v2f){ 0.0f, 0.0f };
    const float bo = b_out[0];

    const v2f* y0v = (const v2f*)(y0 + trial * NU);
    v2f yy = y0v[la];

    const float NS = 0.09486832980505138f; // 0.15 * sqrt(2*0.2)

    bool licked = false, instr_fired = false;
    int  lick_t = TT + 1;

    const float* nbase = noise + trial * (TT * NU);
    v2f en = ((const v2f*)nbase)[la];          // t=0 prefetch (8B load)

    // output section pointers (flat tuple order)
    float* uout  = out;                        // B*T*7
    float* tout  = out  + BB * TT * NI;        // B*T
    float* rout  = tout + BB * TT;             // B*T
    float* lout  = rout + BB * TT;             // B
    float* dout  = lout + BB;                  // B
    float* zout  = dout + BB;                  // B*T
    float* yfout = zout + BB * TT;             // B*100

    for (int t = 0; t < TT; ++t) {
        const v2f e = en;
        if (t < TT - 1)
            en = ((const v2f*)(nbase + (t + 1) * NU))[la];

        const float sm = (t >= 10 && t < 15) ? 1.0f : 0.0f;  // stim_mask
        const float rm = (t >= 20 && t < 35) ? 1.0f : 0.0f;  // resp_mask

        // reward routing (state from previous step), wave-uniform
        const bool delivered    = instr_fired || (licked && is_rew);
        const bool fire         = instr_b && !delivered && (t == 30);
        instr_fired             = instr_fired || fire;
        const bool instr_active = instr_fired && (t >= 30) && (t < 35);
        const bool lick_dyn     = licked && (t > lick_t) && (t < lick_t + 5);
        const float a_rew  = (instr_active ? 1.0f : 0.0f) + ((lick_dyn && is_rew) ? 1.0f : 0.0f);
        const float a_lick = lick_dyn ? 1.0f : 0.0f;

        v2f accA0 = br + rm * wi6 + sm * wis + a_rew * wr + a_lick * wl + NS * e;
        v2f accA1 = { 0.0f, 0.0f };
        v2f accB0 = { 0.0f, 0.0f };
        v2f accB1 = { 0.0f, 0.0f };

        FOR50(MAC)   // 100 readlane + 100 pk_fma

        const v2f pre = (accA0 + accA1) + (accB0 + accB1);
        const v2f prer = { fmaxf(pre.x, 0.0f), fmaxf(pre.y, 0.0f) };
        yy = 0.8f * yy + 0.2f * prer;

        // z = sigmoid(y . w_out + b_out) — DPP wave64 reduction (no LDS):
        // row_shr 1/2/4/8 -> row sums at lane 15 of each row;
        // row_bcast15 (rows 1,3) ; row_bcast31 (rows 2,3) -> lane 63 = total.
        float part = yy.x * wo.x + yy.y * wo.y;
        DPPADD(0x111, 0xf)   // row_shr:1
        DPPADD(0x112, 0xf)   // row_shr:2
        DPPADD(0x114, 0xf)   // row_shr:4
        DPPADD(0x118, 0xf)   // row_shr:8
        DPPADD(0x142, 0xa)   // row_bcast:15 -> rows 1,3
        DPPADD(0x143, 0xc)   // row_bcast:31 -> rows 2,3
        const float x = RL(part, 63) + bo;     // uniform via SGPR
        const float z = 1.0f / (1.0f + expf(-x));

        const bool in_resp = (t >= 20) && (t < 35);
        const bool trig    = in_resp && !licked && (z > 0.5f);
        if (trig) lick_t = t;          // wave-uniform
        licked = licked || trig;
        const bool u5 = licked && (t >= lick_t) && (t < lick_t + 5);
        const bool u4 = instr_active || (u5 && is_rew);

        // per-step outputs
        const int bt = trial * TT + t;
        if (lane < NI) {
            float uv = 0.0f;
            if (lane == stim) uv = sm;                 // stim in [0,4)
            if (lane == 4)    uv = u4 ? 1.0f : 0.0f;
            if (lane == 5)    uv = u5 ? 1.0f : 0.0f;
            if (lane == 6)    uv = rm;
            uout[bt * NI + lane] = uv;
        } else if (lane == 8) {
            tout[bt] = is_rew ? rm : 0.0f;
        } else if (lane == 9) {
            rout[bt] = rm;
        } else if (lane == 10) {
            zout[bt] = z;
        }
    }

    if (lane == 0) {
        lout[trial] = licked ? 1.0f : 0.0f;
        dout[trial] = (instr_fired || (licked && is_rew)) ? 1.0f : 0.0f;
    }
    if (act)
        ((v2f*)(yfout + trial * NU))[la] = yy;   // 8B store, units 2l/2l+1
}

extern "C" void kernel_launch(void* const* d_in, const int* in_sizes, int n_in,
                              void* d_out, int out_size, void* d_ws, size_t ws_size,
                              hipStream_t stream) {
    const float* y0       = (const float*)d_in[0];
    const float* noise    = (const float*)d_in[1];
    const int*   stim     = (const int*)  d_in[2];
    const int*   rew      = (const int*)  d_in[3];
    const int*   instr    = (const int*)  d_in[4];
    const float* W_in_raw = (const float*)d_in[5];
    const float* W_rec    = (const float*)d_in[6];
    const float* b_rec    = (const float*)d_in[7];
    const float* w_out    = (const float*)d_in[8];
    const float* b_out    = (const float*)d_in[9];
    float* out = (float*)d_out;

    drr_kernel<<<BB / 4, 256, 0, stream>>>(y0, noise, stim, rew, instr,
                                           W_in_raw, W_rec, b_rec, w_out, b_out, out);
}